// Round 8
// baseline (203.788 us; speedup 1.0000x reference)
//
#include <hip/hip_runtime.h>
#include <math.h>

// Problem constants (fixed by setup_inputs)
#define B_    2
#define L_    4096
#define H_    8
#define D_    64
#define S_    45      // sample_k
#define NT_   45      // n_top
#define BH_   16      // B*H
#define CHV   64      // cumsum chunk length
#define NCHV  64      // L_/CHV
#define KC    128     // attention key-chunk length
#define NKC   32      // L_/KC
#define SCALE 0.125f  // 1/sqrt(64)
#define NEG_BIG (-1e30f)

// Workspace layout (float element offsets; ints share the same 4B slots).
// VSUM is only live between kA_v and kB_scan; CTXP is written in kC, so
// VSUM overlays the start of the CTXP region. Total ~6.35 MB (proven size).
#define OFF_M     0         // 65536 floats: M[bh][q]
#define OFF_MTOP  65536     // 720 ints:    M_top[bh][u]
#define OFF_MPART 66304     // 23040 floats: m partial [bh][u][kc]
#define OFF_SPART 89344     // 23040 floats: sumexp partial [bh][u][kc]
#define OFF_CTXP  112384    // 1474560 floats: ctx partial [bh][kc][u][d]
#define OFF_VSUM  112384    // 65536 floats: vsum[bh][ch][d] (overlays CTXP)

// DPP row-rotate combine: rotations by 1,2,4,8 within a 16-lane row.
// VALU-pipe (no ds_swizzle), full-rate.
template <int CTRL>
__device__ __forceinline__ float dpp_ror_f(float x) {
    int y = __builtin_amdgcn_update_dpp(0, __float_as_int(x), CTRL, 0xF, 0xF, false);
    return __int_as_float(y);
}

// bf16 <-> f32 bit tricks (bf16 = high 16 bits of fp32; truncation rounding)
__device__ __forceinline__ unsigned short f2bf(float x) {
    return (unsigned short)(__float_as_uint(x) >> 16);
}
__device__ __forceinline__ float bflo(unsigned u) {   // low 16 bits -> f32
    return __uint_as_float(u << 16);
}
__device__ __forceinline__ float bfhi(unsigned u) {   // high 16 bits -> f32
    return __uint_as_float(u & 0xffff0000u);
}

// ---------------------------------------------------------------------------
// kA_m: M[b,h,q] for all 8 h of a q-PAIR. Block = (b, q-pair, hh), 256 thr
// = 4 waves (qsel x sample-half). XCD-slab swizzle: blockIdx%8 = XCD;
// slab (b,hh) = 4MB = one XCD-pair's L2. Sample indices pre-scaled to BYTE
// offsets in LDS (one v_add per gather address). Per sample one coalesced
// 1KB load covers 4 heads; dot4 + 4-step DPP reduce in 16-lane head groups.
// ---------------------------------------------------------------------------
__global__ __launch_bounds__(256) void kA_m(const float* __restrict__ Q,
                                            const float* __restrict__ Kt,
                                            const int* __restrict__ samp,
                                            float* __restrict__ ws)
{
    int tid  = threadIdx.x;
    int w    = tid >> 6;          // 0..3
    int lane = tid & 63;

    int i    = blockIdx.x;
    int xcd  = i & 7;
    int b    = xcd >> 2;
    int hh   = (xcd >> 1) & 1;
    int qs   = ((i >> 3) << 2) | ((xcd & 1) << 1);   // base q (covers qs, qs+1)

    int qsel = w >> 1;            // which q of the pair
    int sh   = w & 1;             // sample-half
    int h4   = lane >> 4;         // head within half
    int q    = qs + qsel;

    __shared__ int   soff[2][S_];             // byte offsets idx*2048
    __shared__ float redm[2][4][2], reds[2][4][2];

    if (sh == 0 && lane < S_)
        soff[qsel][lane] = samp[(qs + qsel) * S_ + lane] << 11;
    __syncthreads();

    const float4 q4 = *(const float4*)(Q +
        ((((long)b * L_ + q) * H_ + hh * 4) << 6) + lane * 4);

    const char* kb_base = (const char*)Kt +
        (long)b * L_ * 2048 + hh * 1024 + lane * 16;

    // sh=0 covers s=0..22, sh=1 covers s=22..44 (s=22 dup: max-safe,
    // masked out of the sum). 24 trips (last clamped), 12-deep batches.
    float mx = NEG_BIG, sm = 0.f;
#pragma unroll
    for (int jb = 0; jb < 24; jb += 12) {
        float4 kb[12];
#pragma unroll
        for (int j = 0; j < 12; ++j) {
            int jj = jb + j;
            int jc = jj < 23 ? jj : 22;            // clamp 24th trip
            int s  = sh * 22 + jc;
            kb[j] = *(const float4*)(kb_base + soff[qsel][s]);
        }
#pragma unroll
        for (int j = 0; j < 12; ++j) {
            int jj = jb + j;
            float p = q4.x * kb[j].x + q4.y * kb[j].y +
                      q4.z * kb[j].z + q4.w * kb[j].w;
            p += dpp_ror_f<0x121>(p);   // ror 1
            p += dpp_ror_f<0x122>(p);   // ror 2
            p += dpp_ror_f<0x124>(p);   // ror 4
            p += dpp_ror_f<0x128>(p);   // ror 8 -> row sum (16 lanes)
            mx = fmaxf(mx, p);          // duplicates harmless for max
            bool valid = (jj < 23) && !(sh == 1 && jj == 0);
            sm += valid ? p : 0.f;
        }
    }
    if ((lane & 15) == 0) { redm[qsel][h4][sh] = mx; reds[qsel][h4][sh] = sm; }
    __syncthreads();
    if (tid < 8) {
        int qq = tid >> 2, hs = tid & 3;
        float m = fmaxf(redm[qq][hs][0], redm[qq][hs][1]);
        float s = reds[qq][hs][0] + reds[qq][hs][1];
        ws[OFF_M + ((long)(b * 8 + hh * 4 + hs)) * L_ + qs + qq] =
            m - s * (1.0f / (float)L_);
    }
}

// ---------------------------------------------------------------------------
// kA_v: per-chunk V sums for the cumsum. Wave per (bh, ch), 16 loads in
// flight. 512 blocks x 128 thr = 1024 units.
// ---------------------------------------------------------------------------
__global__ __launch_bounds__(128) void kA_v(const float* __restrict__ V,
                                            float* __restrict__ ws)
{
    int tid  = threadIdx.x;
    int w    = tid >> 6;
    int lane = tid & 63;
    int unit = blockIdx.x * 2 + w;     // 0..1023
    int bh = unit >> 6, ch = unit & 63;
    int b = bh >> 3, h = bh & 7;
    int d = lane;
    const float* vp = V + ((((long)b * L_ + (long)ch * CHV) * H_ + h) << 6) + d;
    float ssum = 0.f;
#pragma unroll
    for (int ib = 0; ib < CHV; ib += 16) {
        float vb[16];
#pragma unroll
        for (int j = 0; j < 16; ++j) vb[j] = vp[(long)(ib + j) * (H_ * D_)];
#pragma unroll
        for (int j = 0; j < 16; ++j) ssum += vb[j];
    }
    ws[OFF_VSUM + unit * 64 + d] = ssum;
}

// ---------------------------------------------------------------------------
// kB_topk: top-45 of M per (b,h). 16 blocks. DPP row-max + ballot/ffs
// argmax; parity-double-buffered LDS merge -> one barrier per round.
// Lowest-index tie-break preserved (lane order == index order).
// ---------------------------------------------------------------------------
__global__ __launch_bounds__(256) void kB_topk(float* __restrict__ ws)
{
    int tid = threadIdx.x;
    int bh = blockIdx.x;
    const float* M = ws + OFF_M + (long)bh * L_;
    int* Mtop = (int*)ws + OFF_MTOP + bh * NT_;

    float vals[16];
#pragma unroll
    for (int j = 0; j < 16; ++j) vals[j] = M[tid * 16 + j];
    float lv = NEG_BIG; int li = tid * 16;
#pragma unroll
    for (int j = 0; j < 16; ++j) {
        if (vals[j] > lv) { lv = vals[j]; li = tid * 16 + j; }
    }

    __shared__ float wbv[2][4];
    __shared__ int   wbi[2][4];
    int lane = tid & 63, w = tid >> 6;

    for (int r = 0; r < NT_; ++r) {
        int par = r & 1;
        float rm = lv;
        rm = fmaxf(rm, dpp_ror_f<0x121>(rm));
        rm = fmaxf(rm, dpp_ror_f<0x122>(rm));
        rm = fmaxf(rm, dpp_ror_f<0x124>(rm));
        rm = fmaxf(rm, dpp_ror_f<0x128>(rm));    // row (16-lane) max
        rm = fmaxf(rm, __shfl_xor(rm, 16));
        float wmax = fmaxf(rm, __shfl_xor(rm, 32));
        unsigned long long bm = __ballot(lv == wmax);
        int winner = __ffsll((unsigned long long)bm) - 1;
        int wi = __shfl(li, winner);
        if (lane == 0) { wbv[par][w] = wmax; wbi[par][w] = wi; }
        __syncthreads();
        float bv = wbv[par][0]; int bi = wbi[par][0];
#pragma unroll
        for (int g = 1; g < 4; ++g) {
            float v2 = wbv[par][g]; int i2 = wbi[par][g];
            if (v2 > bv || (v2 == bv && i2 < bi)) { bv = v2; bi = i2; }
        }
        if (tid == 0) Mtop[r] = bi;
        if ((bi >> 4) == tid) {
#pragma unroll
            for (int j = 0; j < 16; ++j)
                if (j == (bi & 15)) vals[j] = NEG_BIG;
            lv = NEG_BIG; li = tid * 16;
#pragma unroll
            for (int j = 0; j < 16; ++j)
                if (vals[j] > lv) { lv = vals[j]; li = tid * 16 + j; }
        }
        // no second barrier: next round writes the other parity slot
    }
}

// ---------------------------------------------------------------------------
// kB_scan: cumsum write: out = prefix-sum of V. Wave per (bh, ch); prefix
// from vsum chunk sums; 16 loads in flight. 256 blocks x 4 waves.
// ---------------------------------------------------------------------------
__global__ __launch_bounds__(256) void kB_scan(const float* __restrict__ V,
                                               float* __restrict__ out,
                                               const float* __restrict__ ws)
{
    int tid = threadIdx.x;
    int w = tid >> 6, d = tid & 63;
    int unit = blockIdx.x * 4 + w;     // 0..1023
    int bh = unit >> 6, ch = unit & 63;
    int b = bh >> 3, h = bh & 7;

    // prefix over earlier chunk sums, 8 loads in flight
    float acc = 0.f;
    {
        const float* vs = ws + OFF_VSUM + (long)bh * NCHV * 64 + d;
        int c = 0;
        for (; c + 8 <= ch; c += 8) {
            float vb[8];
#pragma unroll
            for (int j = 0; j < 8; ++j) vb[j] = vs[(c + j) * 64];
#pragma unroll
            for (int j = 0; j < 8; ++j) acc += vb[j];
        }
        for (; c < ch; ++c) acc += vs[c * 64];
    }

    const float* vp = V   + ((((long)b * L_ + (long)ch * CHV) * H_ + h) << 6) + d;
    float*       op = out + ((((long)b * L_ + (long)ch * CHV) * H_ + h) << 6) + d;
#pragma unroll
    for (int ib = 0; ib < CHV; ib += 16) {
        float vb[16];
#pragma unroll
        for (int j = 0; j < 16; ++j) vb[j] = vp[(long)(ib + j) * (H_ * D_)];
#pragma unroll
        for (int j = 0; j < 16; ++j) {
            acc += vb[j];
            op[(long)(ib + j) * (H_ * D_)] = acc;
        }
    }
}

// ---------------------------------------------------------------------------
// kC: attention partials. Block = (bh, kc, ug): ~23 selected queries vs one
// 128-key chunk -> 1024 blocks. K + P in LDS as BF16 (24.4 KB total; top-k
// selection already fixed, bf16 error << threshold). Q rows via
// readfirstlane-uniform base. PV reads P as 8-wide bf16 b128 broadcast.
// NO min-waves launch bound (R5 lesson: forcing it caused scratch spills).
// ---------------------------------------------------------------------------
#define KPAD16 72   // bf16 row stride: 144B, 16B-aligned
#define NUH    23   // max queries per block (ug=0: 23, ug=1: 22)
__global__ __launch_bounds__(256) void kC(const float* __restrict__ Q,
                                          const float* __restrict__ Kt,
                                          const float* __restrict__ V,
                                          float* __restrict__ ws)
{
    __shared__ unsigned short Klds16[KC * KPAD16];  // 18432 B
    __shared__ unsigned short P16[NUH * KC];        // 5888 B
    __shared__ int qpos[NUH];

    int tid = threadIdx.x;
    int bh = blockIdx.x >> 6;
    int kc = (blockIdx.x >> 1) & 31;
    int ug = blockIdx.x & 1;
    int b = bh >> 3, h = bh & 7;
    int kbase = kc * KC;
    int u0 = ug * 23;
    int NU = ug ? 22 : 23;             // u in [u0, u0+NU)

    if (tid < NU) qpos[tid] = ((const int*)ws)[OFF_MTOP + bh * NT_ + tid + u0];

    // coalesced K-chunk staging: float4 global reads -> packed bf16 LDS
    {
        const float4* ksrc4 = (const float4*)(Kt + ((((long)b * L_ + kbase) * H_ + h) << 6));
#pragma unroll
        for (int i = 0; i < 8; ++i) {
            int e = i * 256 + tid;         // 0..2047 float4 slots
            int r = e >> 4, c4 = e & 15;   // row, float4-within-row
            float4 kv = ksrc4[(long)r * (H_ * D_ / 4) + c4];
            uint2 pk;
            pk.x = (__float_as_uint(kv.x) >> 16) | (__float_as_uint(kv.y) & 0xffff0000u);
            pk.y = (__float_as_uint(kv.z) >> 16) | (__float_as_uint(kv.w) & 0xffff0000u);
            *(uint2*)&Klds16[r * KPAD16 + c4 * 4] = pk;
        }
    }
    __syncthreads();

    // QK: thread = (k, uh in {0,1}); K row unpacked from LDS bf16 into 64
    // fp32 VGPRs once; Q rows via uniform (readfirstlane) base. Fixed 12
    // trips (clamped dup: benign same-thread rewrite). 4-way accumulators.
    int k = tid & 127, uh = tid >> 7;
    int kpos = kbase + k;
    {
        float kf[64];
#pragma unroll
        for (int j = 0; j < 8; ++j) {
            uint4 U = *(const uint4*)&Klds16[k * KPAD16 + j * 8];
            kf[j*8+0] = bflo(U.x); kf[j*8+1] = bfhi(U.x);
            kf[j*8+2] = bflo(U.y); kf[j*8+3] = bfhi(U.y);
            kf[j*8+4] = bflo(U.z); kf[j*8+5] = bfhi(U.z);
            kf[j*8+6] = bflo(U.w); kf[j*8+7] = bfhi(U.w);
        }

#pragma unroll 3
        for (int j = 0; j < 12; ++j) {
            int ul = uh * 12 + j;
            if (ul > NU - 1) ul = NU - 1;          // clamp (dup write, same val)
            int qp_ = __builtin_amdgcn_readfirstlane(qpos[ul]);
            const float4* qrow = (const float4*)(Q + ((((long)b * L_ + qp_) * H_ + h) << 6));
            float a0 = 0.f, a1 = 0.f, a2 = 0.f, a3 = 0.f;
#pragma unroll
            for (int jj = 0; jj < 16; jj += 4) {
                float4 q0 = qrow[jj + 0], q1 = qrow[jj + 1];
                float4 q2 = qrow[jj + 2], q3 = qrow[jj + 3];
                a0 += q0.x * kf[jj*4+ 0] + q0.y * kf[jj*4+ 1] +
                      q0.z * kf[jj*4+ 2] + q0.w * kf[jj*4+ 3];
                a1 += q1.x * kf[jj*4+ 4] + q1.y * kf[jj*4+ 5] +
                      q1.z * kf[jj*4+ 6] + q1.w * kf[jj*4+ 7];
                a2 += q2.x * kf[jj*4+ 8] + q2.y * kf[jj*4+ 9] +
                      q2.z * kf[jj*4+10] + q2.w * kf[jj*4+11];
                a3 += q3.x * kf[jj*4+12] + q3.y * kf[jj*4+13] +
                      q3.z * kf[jj*4+14] + q3.w * kf[jj*4+15];
            }
            float sc = ((a0 + a1) + (a2 + a3)) * SCALE;
            if (kpos > qp_) sc = NEG_BIG;   // causal mask
            P16[ul * KC + k] = f2bf(sc);
        }
    }
    __syncthreads();

    // per-u softmax partials (wave w handles ul = w, w+4, ...). Sum uses the
    // bf16-truncated e values so T matches what PV accumulates.
    int lane = tid & 63, w = tid >> 6;
    for (int ul = w; ul < NU; ul += 4) {
        float s0 = bflo(P16[ul * KC + lane]);
        float s1 = bflo(P16[ul * KC + 64 + lane]);
        float m = fmaxf(s0, s1);
#pragma unroll
        for (int off = 32; off; off >>= 1) m = fmaxf(m, __shfl_xor(m, off));
        float e0 = __expf(s0 - m), e1 = __expf(s1 - m);
        unsigned short b0 = f2bf(e0), b1 = f2bf(e1);
        P16[ul * KC + lane]      = b0;
        P16[ul * KC + 64 + lane] = b1;
        float sm = bflo(b0) + bflo(b1);
#pragma unroll
        for (int off = 32; off; off >>= 1) sm += __shfl_xor(sm, off);
        if (lane == 0) {
            ws[OFF_MPART + ((long)bh * NT_ + u0 + ul) * NKC + kc] = m;
            ws[OFF_SPART + ((long)bh * NT_ + u0 + ul) * NKC + kc] = sm;
        }
    }
    __syncthreads();

    // PV: wave w accumulates ctx for ul in {w, w+4, ...} (<=6); lane = d.
    // V from global (coalesced 256B/instr); P as 8-wide bf16 b128 broadcast.
    {
        const float* vsrc = V + ((((long)b * L_ + kbase) * H_ + h) << 6);
        float ctx[6];
#pragma unroll
        for (int j = 0; j < 6; ++j) ctx[j] = 0.f;
        for (int kk8 = 0; kk8 < 16; ++kk8) {
            float v[8];
#pragma unroll
            for (int t = 0; t < 8; ++t)
                v[t] = vsrc[(long)(kk8 * 8 + t) * (H_ * D_) + lane];
#pragma unroll
            for (int j = 0; j < 6; ++j) {
                int ul = w + j * 4;
                if (ul < NU) {
                    uint4 U = *(const uint4*)&P16[ul * KC + kk8 * 8];  // broadcast
                    ctx[j] += bflo(U.x) * v[0] + bfhi(U.x) * v[1]
                            + bflo(U.y) * v[2] + bfhi(U.y) * v[3]
                            + bflo(U.z) * v[4] + bfhi(U.z) * v[5]
                            + bflo(U.w) * v[6] + bfhi(U.w) * v[7];
                }
            }
        }
#pragma unroll
        for (int j = 0; j < 6; ++j) {
            int ul = w + j * 4;
            if (ul < NU)
                ws[OFF_CTXP + ((long)(bh * NKC + kc) * NT_ + u0 + ul) * 64 + lane] = ctx[j];
        }
    }
}

// ---------------------------------------------------------------------------
// kD: merge chunk partials (log-sum-exp) and overwrite selected rows.
// One 64-thread block per (bh,u) unit: 720 blocks.
// ---------------------------------------------------------------------------
__global__ __launch_bounds__(64) void kD(float* __restrict__ out,
                                         const float* __restrict__ ws)
{
    int lane = threadIdx.x;
    int unit = blockIdx.x;               // 0..719
    int bh = unit / NT_, u = unit - bh * NT_;
    int b = bh >> 3, h = bh & 7;

    const float4* mp4 = (const float4*)(ws + OFF_MPART + ((long)bh * NT_ + u) * NKC);
    const float4* sp4 = (const float4*)(ws + OFF_SPART + ((long)bh * NT_ + u) * NKC);

    float mc[NKC], sc[NKC];
    float m = NEG_BIG;
#pragma unroll
    for (int c4 = 0; c4 < NKC / 4; ++c4) {
        float4 mv = mp4[c4];
        float4 sv = sp4[c4];
        mc[c4 * 4 + 0] = mv.x; mc[c4 * 4 + 1] = mv.y;
        mc[c4 * 4 + 2] = mv.z; mc[c4 * 4 + 3] = mv.w;
        sc[c4 * 4 + 0] = sv.x; sc[c4 * 4 + 1] = sv.y;
        sc[c4 * 4 + 2] = sv.z; sc[c4 * 4 + 3] = sv.w;
        m = fmaxf(m, fmaxf(fmaxf(mv.x, mv.y), fmaxf(mv.z, mv.w)));
    }
    float T = 0.f, ctx = 0.f;
#pragma unroll
    for (int c = 0; c < NKC; ++c) {
        float wgt = __expf(mc[c] - m);   // fully-masked chunks: exp(-1e30-m) = 0
        T   += sc[c] * wgt;
        ctx += ws[OFF_CTXP + ((long)(bh * NKC + c) * NT_ + u) * 64 + lane] * wgt;
    }
    int qp = ((const int*)ws)[OFF_MTOP + bh * NT_ + u];
    out[((((long)b * L_ + qp) * H_ + h) << 6) + lane] = ctx / T;
}

// ---------------------------------------------------------------------------
extern "C" void kernel_launch(void* const* d_in, const int* in_sizes, int n_in,
                              void* d_out, int out_size, void* d_ws, size_t ws_size,
                              hipStream_t stream)
{
    const float* Q    = (const float*)d_in[0];
    const float* K    = (const float*)d_in[1];
    const float* V    = (const float*)d_in[2];
    const int*   samp = (const int*)d_in[4];   // d_in[3] = attn_mask (unused)
    float* out = (float*)d_out;
    float* ws  = (float*)d_ws;

    // M scores: 8192 blocks = (b, q-pair, hh), XCD-slab swizzled, 4 waves
    kA_m<<<8192, 256, 0, stream>>>(Q, K, samp, ws);
    // V chunk sums: 512 blocks x 2 waves = 1024 (bh,ch) units
    kA_v<<<512, 128, 0, stream>>>(V, ws);
    // top-45 per (b,h): 16 blocks
    kB_topk<<<16, 256, 0, stream>>>(ws);
    // cumsum write: 256 blocks x 4 waves
    kB_scan<<<256, 256, 0, stream>>>(V, out, ws);
    // attention partials: 16 bh x 32 key chunks x 2 u-halves
    kC<<<1024, 256, 0, stream>>>(Q, K, V, ws);
    // merge + scatter selected rows: 720 x 64-thread blocks
    kD<<<720, 64, 0, stream>>>(out, ws);
}

// Round 9
// 188.910 us; speedup vs baseline: 1.0788x; 1.0788x over previous
//
#include <hip/hip_runtime.h>
#include <math.h>

// Problem constants (fixed by setup_inputs)
#define B_    2
#define L_    4096
#define H_    8
#define D_    64
#define S_    45      // sample_k
#define NT_   45      // n_top
#define BH_   16      // B*H
#define CHV   64      // cumsum chunk length
#define NCHV  64      // L_/CHV
#define KC    128     // attention key-chunk length
#define NKC   32      // L_/KC
#define SCALE 0.125f  // 1/sqrt(64)
#define NEG_BIG (-1e30f)

// Workspace layout (float element offsets; ints share the same 4B slots).
// VSUM is only live between k1 and k2-scan; CTXP is written in kC, so
// VSUM overlays the start of the CTXP region. Total ~6.35 MB.
#define OFF_M     0         // 65536 floats: M[bh][q]
#define OFF_MTOP  65536     // 720 ints:    M_top[bh][u]
#define OFF_MPART 66304     // 23040 floats: m partial [bh][u][kc]
#define OFF_SPART 89344     // 23040 floats: sumexp partial [bh][u][kc]
#define OFF_CTXP  112384    // 1474560 floats: ctx partial [bh][kc][u][d]
#define OFF_VSUM  112384    // 65536 floats: vsum[bh][ch][d] (overlays CTXP)

// DPP row-rotate combine within a 16-lane row (VALU-pipe, no ds_swizzle)
template <int CTRL>
__device__ __forceinline__ float dpp_ror_f(float x) {
    int y = __builtin_amdgcn_update_dpp(0, __float_as_int(x), CTRL, 0xF, 0xF, false);
    return __int_as_float(y);
}

// bf16 <-> f32 bit tricks (bf16 = high 16 bits of fp32; truncation rounding)
__device__ __forceinline__ unsigned short f2bf(float x) {
    return (unsigned short)(__float_as_uint(x) >> 16);
}
__device__ __forceinline__ float bflo(unsigned u) { return __uint_as_float(u << 16); }
__device__ __forceinline__ float bfhi(unsigned u) { return __uint_as_float(u & 0xffff0000u); }

// ---------------------------------------------------------------------------
// k1: FUSED  (a) M scores: blocks < 4096, block = (b, q-quad, hh), wave = one
//     q. XCD-slab swizzle (blockIdx%8 = XCD; slab (b,hh) = 4MB = one XCD L2).
//     Per sample one coalesced 1KB gather covers 4 heads (lane = 16B chunk);
//     dot4 + 4-step DPP reduce per 16-lane head group. All 45 samples in one
//     wave: no clamp/select, no cross-wave reduce, ONE barrier total.
//     (b) V chunk sums: blocks >= 4096 (256 blocks x 4 waves).
// ---------------------------------------------------------------------------
__global__ __launch_bounds__(256) void k1(const float* __restrict__ Q,
                                          const float* __restrict__ Kt,
                                          const float* __restrict__ V,
                                          const int* __restrict__ samp,
                                          float* __restrict__ ws)
{
    int tid  = threadIdx.x;
    int w    = tid >> 6;          // 0..3
    int lane = tid & 63;

    if (blockIdx.x < 4096) {
        int i   = blockIdx.x;
        int xcd = i & 7;
        int b   = xcd >> 2;
        int hh  = (xcd >> 1) & 1;
        int qq  = ((i >> 3) << 1) | (xcd & 1);   // q-quad index 0..1023

        __shared__ int soff[4][S_];              // byte offsets idx*2048
        if (tid < 4 * S_) {
            int qs = tid / S_, ss = tid - qs * S_;
            soff[qs][ss] = samp[(qq * 4 + qs) * S_ + ss] << 11;
        }
        __syncthreads();

        int q  = qq * 4 + w;                     // wave owns one q
        int h4 = lane >> 4;                      // head within half

        const float4 q4 = *(const float4*)(Q +
            ((((long)b * L_ + q) * H_ + hh * 4) << 6) + lane * 4);

        const char* kb_base = (const char*)Kt +
            (long)b * L_ * 2048 + hh * 1024 + lane * 16;

        float mx = NEG_BIG, sm = 0.f;
#pragma unroll
        for (int jb = 0; jb < 45; jb += 15) {    // 3 batches x 15 gathers
            float4 kb[15];
#pragma unroll
            for (int j = 0; j < 15; ++j)
                kb[j] = *(const float4*)(kb_base + soff[w][jb + j]);
#pragma unroll
            for (int j = 0; j < 15; ++j) {
                float p = q4.x * kb[j].x + q4.y * kb[j].y +
                          q4.z * kb[j].z + q4.w * kb[j].w;
                p += dpp_ror_f<0x121>(p);   // ror 1
                p += dpp_ror_f<0x122>(p);   // ror 2
                p += dpp_ror_f<0x124>(p);   // ror 4
                p += dpp_ror_f<0x128>(p);   // ror 8 -> 16-lane row sum
                mx = fmaxf(mx, p);
                sm += p;
            }
        }
        if ((lane & 15) == 0)
            ws[OFF_M + ((long)(b * 8 + hh * 4 + h4)) * L_ + q] =
                mx - sm * (1.0f / (float)L_);
    } else {
        // V chunk sums: wave per (bh, ch), 16 loads in flight
        int unit = (blockIdx.x - 4096) * 4 + w;   // 0..1023
        int bh = unit >> 6, ch = unit & 63;
        int b = bh >> 3, h = bh & 7;
        const float* vp = V + ((((long)b * L_ + (long)ch * CHV) * H_ + h) << 6) + lane;
        float ssum = 0.f;
#pragma unroll
        for (int ib = 0; ib < CHV; ib += 16) {
            float vb[16];
#pragma unroll
            for (int j = 0; j < 16; ++j) vb[j] = vp[(long)(ib + j) * (H_ * D_)];
#pragma unroll
            for (int j = 0; j < 16; ++j) ssum += vb[j];
        }
        ws[OFF_VSUM + unit * 64 + lane] = ssum;
    }
}

// ---------------------------------------------------------------------------
// k2: FUSED  (a) top-45 per (b,h): blocks < 16. Each of 4 waves does a
//     barrier-free iterative argmax over its 1024-element quarter (lane-major
//     index order -> ballot lowest-lane = lowest index), producing a sorted
//     45-list in LDS; then a 4-lane shfl merge (g-ascending tie-break =
//     lowest global index). TWO barriers total instead of 45.
//     (b) cumsum write: blocks >= 16 (256 blocks x 4 waves).
// ---------------------------------------------------------------------------
__global__ __launch_bounds__(256) void k2(const float* __restrict__ V,
                                          float* __restrict__ out,
                                          float* __restrict__ ws)
{
    int tid  = threadIdx.x;
    int w    = tid >> 6;
    int lane = tid & 63;

    if (blockIdx.x < 16) {
        int bh = blockIdx.x;
        int* Mtop = (int*)ws + OFF_MTOP + bh * NT_;

        __shared__ float lv_[4][NT_];
        __shared__ int   li_[4][NT_];

        // load 16 consecutive M values per lane (lane-major ordering)
        const float4* m4 = (const float4*)(ws + OFF_M + (long)bh * L_ +
                                           w * 1024 + lane * 16);
        float vals[16];
        {
            float4 a = m4[0], bq = m4[1], c = m4[2], d = m4[3];
            vals[0]=a.x; vals[1]=a.y; vals[2]=a.z; vals[3]=a.w;
            vals[4]=bq.x; vals[5]=bq.y; vals[6]=bq.z; vals[7]=bq.w;
            vals[8]=c.x; vals[9]=c.y; vals[10]=c.z; vals[11]=c.w;
            vals[12]=d.x; vals[13]=d.y; vals[14]=d.z; vals[15]=d.w;
        }
        float lv = NEG_BIG; int li = lane * 16;
#pragma unroll
        for (int j = 0; j < 16; ++j)
            if (vals[j] > lv) { lv = vals[j]; li = lane * 16 + j; }

        // 45 wave-synchronous argmax rounds (no barriers)
        for (int r = 0; r < NT_; ++r) {
            float rm = lv;
            rm = fmaxf(rm, dpp_ror_f<0x121>(rm));
            rm = fmaxf(rm, dpp_ror_f<0x122>(rm));
            rm = fmaxf(rm, dpp_ror_f<0x124>(rm));
            rm = fmaxf(rm, dpp_ror_f<0x128>(rm));
            rm = fmaxf(rm, __shfl_xor(rm, 16));
            rm = fmaxf(rm, __shfl_xor(rm, 32));      // wave max in all lanes
            unsigned long long bm = __ballot(lv == rm);
            int winner = __ffsll(bm) - 1;            // lowest lane = lowest idx
            int wi = __shfl(li, winner);
            if (lane == 0) { lv_[w][r] = rm; li_[w][r] = w * 1024 + wi; }
            if (lane == winner) {
#pragma unroll
                for (int j = 0; j < 16; ++j)
                    if (j == (wi & 15)) vals[j] = NEG_BIG;
                lv = NEG_BIG; li = lane * 16;
#pragma unroll
                for (int j = 0; j < 16; ++j)
                    if (vals[j] > lv) { lv = vals[j]; li = lane * 16 + j; }
            }
        }
        __syncthreads();

        // merge 4 sorted lists with 4 lanes of wave 0
        if (w == 0) {
            int g = lane & 3;
            int p = 0;
            float hv = lv_[g][0]; int hi = li_[g][0];
            for (int r = 0; r < NT_; ++r) {
                float v0 = __shfl(hv, 0), v1 = __shfl(hv, 1),
                      v2 = __shfl(hv, 2), v3 = __shfl(hv, 3);
                int   i0 = __shfl(hi, 0), i1 = __shfl(hi, 1),
                      i2 = __shfl(hi, 2), i3 = __shfl(hi, 3);
                // g-ascending scan with strict > : tie -> lower g -> lower idx
                float bv = v0; int bi = i0, bg = 0;
                if (v1 > bv) { bv = v1; bi = i1; bg = 1; }
                if (v2 > bv) { bv = v2; bi = i2; bg = 2; }
                if (v3 > bv) { bv = v3; bi = i3; bg = 3; }
                if (lane == 0) Mtop[r] = bi;
                if (g == bg) {
                    ++p;
                    hv = (p < NT_) ? lv_[g][p] : NEG_BIG;
                    hi = (p < NT_) ? li_[g][p] : 0;
                }
            }
        }
    } else {
        // cumsum write: wave per (bh, ch); prefix from vsum chunk sums
        int unit = (blockIdx.x - 16) * 4 + w;    // 0..1023
        int bh = unit >> 6, ch = unit & 63;
        int b = bh >> 3, h = bh & 7;
        int d = lane;

        float acc = 0.f;
        {
            const float* vs = ws + OFF_VSUM + (long)bh * NCHV * 64 + d;
            int c = 0;
            for (; c + 8 <= ch; c += 8) {
                float vb[8];
#pragma unroll
                for (int j = 0; j < 8; ++j) vb[j] = vs[(c + j) * 64];
#pragma unroll
                for (int j = 0; j < 8; ++j) acc += vb[j];
            }
            for (; c < ch; ++c) acc += vs[c * 64];
        }

        const float* vp = V   + ((((long)b * L_ + (long)ch * CHV) * H_ + h) << 6) + d;
        float*       op = out + ((((long)b * L_ + (long)ch * CHV) * H_ + h) << 6) + d;
#pragma unroll
        for (int ib = 0; ib < CHV; ib += 16) {
            float vb[16];
#pragma unroll
            for (int j = 0; j < 16; ++j) vb[j] = vp[(long)(ib + j) * (H_ * D_)];
#pragma unroll
            for (int j = 0; j < 16; ++j) {
                acc += vb[j];
                op[(long)(ib + j) * (H_ * D_)] = acc;
            }
        }
    }
}

// ---------------------------------------------------------------------------
// kC: attention partials. Block = (bh, kc, ug): ~23 selected queries vs one
// 128-key chunk -> 1024 blocks. K + P in LDS as BF16 (24.4 KB; selection is
// already fixed, bf16 error << threshold). Q rows via readfirstlane-uniform
// base. PV reads P as 8-wide bf16 b128 broadcast. No min-waves bound (R5
// lesson: forcing it caused scratch spills).
// ---------------------------------------------------------------------------
#define KPAD16 72   // bf16 row stride: 144B, 16B-aligned
#define NUH    23
__global__ __launch_bounds__(256) void kC(const float* __restrict__ Q,
                                          const float* __restrict__ Kt,
                                          const float* __restrict__ V,
                                          float* __restrict__ ws)
{
    __shared__ unsigned short Klds16[KC * KPAD16];  // 18432 B
    __shared__ unsigned short P16[NUH * KC];        // 5888 B
    __shared__ int qpos[NUH];

    int tid = threadIdx.x;
    int bh = blockIdx.x >> 6;
    int kc = (blockIdx.x >> 1) & 31;
    int ug = blockIdx.x & 1;
    int b = bh >> 3, h = bh & 7;
    int kbase = kc * KC;
    int u0 = ug * 23;
    int NU = ug ? 22 : 23;

    if (tid < NU) qpos[tid] = ((const int*)ws)[OFF_MTOP + bh * NT_ + tid + u0];

    // coalesced K-chunk staging: float4 global reads -> packed bf16 LDS
    {
        const float4* ksrc4 = (const float4*)(Kt + ((((long)b * L_ + kbase) * H_ + h) << 6));
#pragma unroll
        for (int i = 0; i < 8; ++i) {
            int e = i * 256 + tid;
            int r = e >> 4, c4 = e & 15;
            float4 kv = ksrc4[(long)r * (H_ * D_ / 4) + c4];
            uint2 pk;
            pk.x = (__float_as_uint(kv.x) >> 16) | (__float_as_uint(kv.y) & 0xffff0000u);
            pk.y = (__float_as_uint(kv.z) >> 16) | (__float_as_uint(kv.w) & 0xffff0000u);
            *(uint2*)&Klds16[r * KPAD16 + c4 * 4] = pk;
        }
    }
    __syncthreads();

    int k = tid & 127, uh = tid >> 7;
    int kpos = kbase + k;
    {
        float kf[64];
#pragma unroll
        for (int j = 0; j < 8; ++j) {
            uint4 U = *(const uint4*)&Klds16[k * KPAD16 + j * 8];
            kf[j*8+0] = bflo(U.x); kf[j*8+1] = bfhi(U.x);
            kf[j*8+2] = bflo(U.y); kf[j*8+3] = bfhi(U.y);
            kf[j*8+4] = bflo(U.z); kf[j*8+5] = bfhi(U.z);
            kf[j*8+6] = bflo(U.w); kf[j*8+7] = bfhi(U.w);
        }

#pragma unroll 3
        for (int j = 0; j < 12; ++j) {
            int ul = uh * 12 + j;
            if (ul > NU - 1) ul = NU - 1;          // clamp (dup write, same val)
            int qp_ = __builtin_amdgcn_readfirstlane(qpos[ul]);
            const float4* qrow = (const float4*)(Q + ((((long)b * L_ + qp_) * H_ + h) << 6));
            float a0 = 0.f, a1 = 0.f, a2 = 0.f, a3 = 0.f;
#pragma unroll
            for (int jj = 0; jj < 16; jj += 4) {
                float4 q0 = qrow[jj + 0], q1 = qrow[jj + 1];
                float4 q2 = qrow[jj + 2], q3 = qrow[jj + 3];
                a0 += q0.x * kf[jj*4+ 0] + q0.y * kf[jj*4+ 1] +
                      q0.z * kf[jj*4+ 2] + q0.w * kf[jj*4+ 3];
                a1 += q1.x * kf[jj*4+ 4] + q1.y * kf[jj*4+ 5] +
                      q1.z * kf[jj*4+ 6] + q1.w * kf[jj*4+ 7];
                a2 += q2.x * kf[jj*4+ 8] + q2.y * kf[jj*4+ 9] +
                      q2.z * kf[jj*4+10] + q2.w * kf[jj*4+11];
                a3 += q3.x * kf[jj*4+12] + q3.y * kf[jj*4+13] +
                      q3.z * kf[jj*4+14] + q3.w * kf[jj*4+15];
            }
            float sc = ((a0 + a1) + (a2 + a3)) * SCALE;
            if (kpos > qp_) sc = NEG_BIG;   // causal mask
            P16[ul * KC + k] = f2bf(sc);
        }
    }
    __syncthreads();

    int lane = tid & 63, w = tid >> 6;
    for (int ul = w; ul < NU; ul += 4) {
        float s0 = bflo(P16[ul * KC + lane]);
        float s1 = bflo(P16[ul * KC + 64 + lane]);
        float m = fmaxf(s0, s1);
#pragma unroll
        for (int off = 32; off; off >>= 1) m = fmaxf(m, __shfl_xor(m, off));
        float e0 = __expf(s0 - m), e1 = __expf(s1 - m);
        unsigned short b0 = f2bf(e0), b1 = f2bf(e1);
        P16[ul * KC + lane]      = b0;
        P16[ul * KC + 64 + lane] = b1;
        float sm = bflo(b0) + bflo(b1);
#pragma unroll
        for (int off = 32; off; off >>= 1) sm += __shfl_xor(sm, off);
        if (lane == 0) {
            ws[OFF_MPART + ((long)bh * NT_ + u0 + ul) * NKC + kc] = m;
            ws[OFF_SPART + ((long)bh * NT_ + u0 + ul) * NKC + kc] = sm;
        }
    }
    __syncthreads();

    {
        const float* vsrc = V + ((((long)b * L_ + kbase) * H_ + h) << 6);
        float ctx[6];
#pragma unroll
        for (int j = 0; j < 6; ++j) ctx[j] = 0.f;
        for (int kk8 = 0; kk8 < 16; ++kk8) {
            float v[8];
#pragma unroll
            for (int t = 0; t < 8; ++t)
                v[t] = vsrc[(long)(kk8 * 8 + t) * (H_ * D_) + lane];
#pragma unroll
            for (int j = 0; j < 6; ++j) {
                int ul = w + j * 4;
                if (ul < NU) {
                    uint4 U = *(const uint4*)&P16[ul * KC + kk8 * 8];
                    ctx[j] += bflo(U.x) * v[0] + bfhi(U.x) * v[1]
                            + bflo(U.y) * v[2] + bfhi(U.y) * v[3]
                            + bflo(U.z) * v[4] + bfhi(U.z) * v[5]
                            + bflo(U.w) * v[6] + bfhi(U.w) * v[7];
                }
            }
        }
#pragma unroll
        for (int j = 0; j < 6; ++j) {
            int ul = w + j * 4;
            if (ul < NU)
                ws[OFF_CTXP + ((long)(bh * NKC + kc) * NT_ + u0 + ul) * 64 + lane] = ctx[j];
        }
    }
}

// ---------------------------------------------------------------------------
// kD: merge chunk partials (log-sum-exp) and overwrite selected rows.
// One 64-thread block per (bh,u) unit: 720 blocks.
// ---------------------------------------------------------------------------
__global__ __launch_bounds__(64) void kD(float* __restrict__ out,
                                         const float* __restrict__ ws)
{
    int lane = threadIdx.x;
    int unit = blockIdx.x;
    int bh = unit / NT_, u = unit - bh * NT_;
    int b = bh >> 3, h = bh & 7;

    const float4* mp4 = (const float4*)(ws + OFF_MPART + ((long)bh * NT_ + u) * NKC);
    const float4* sp4 = (const float4*)(ws + OFF_SPART + ((long)bh * NT_ + u) * NKC);

    float mc[NKC], sc[NKC];
    float m = NEG_BIG;
#pragma unroll
    for (int c4 = 0; c4 < NKC / 4; ++c4) {
        float4 mv = mp4[c4];
        float4 sv = sp4[c4];
        mc[c4 * 4 + 0] = mv.x; mc[c4 * 4 + 1] = mv.y;
        mc[c4 * 4 + 2] = mv.z; mc[c4 * 4 + 3] = mv.w;
        sc[c4 * 4 + 0] = sv.x; sc[c4 * 4 + 1] = sv.y;
        sc[c4 * 4 + 2] = sv.z; sc[c4 * 4 + 3] = sv.w;
        m = fmaxf(m, fmaxf(fmaxf(mv.x, mv.y), fmaxf(mv.z, mv.w)));
    }
    float T = 0.f, ctx = 0.f;
#pragma unroll
    for (int c = 0; c < NKC; ++c) {
        float wgt = __expf(mc[c] - m);
        T   += sc[c] * wgt;
        ctx += ws[OFF_CTXP + ((long)(bh * NKC + c) * NT_ + u) * 64 + lane] * wgt;
    }
    int qp = ((const int*)ws)[OFF_MTOP + bh * NT_ + u];
    out[((((long)b * L_ + qp) * H_ + h) << 6) + lane] = ctx / T;
}

// ---------------------------------------------------------------------------
extern "C" void kernel_launch(void* const* d_in, const int* in_sizes, int n_in,
                              void* d_out, int out_size, void* d_ws, size_t ws_size,
                              hipStream_t stream)
{
    const float* Q    = (const float*)d_in[0];
    const float* K    = (const float*)d_in[1];
    const float* V    = (const float*)d_in[2];
    const int*   samp = (const int*)d_in[4];   // d_in[3] = attn_mask (unused)
    float* out = (float*)d_out;
    float* ws  = (float*)d_ws;

    // 1: M scores (4096 blocks, wave = one q) + V chunk sums (256 blocks)
    k1<<<4352, 256, 0, stream>>>(Q, K, V, samp, ws);
    // 2: top-45 (16 blocks) overlapped with cumsum write (256 blocks)
    k2<<<272, 256, 0, stream>>>(V, out, ws);
    // 3: attention partials (16 bh x 32 key chunks x 2 u-halves)
    kC<<<1024, 256, 0, stream>>>(Q, K, V, ws);
    // 4: merge + scatter selected rows (720 x 64-thread blocks)
    kD<<<720, 64, 0, stream>>>(out, ws);
}